// Round 5
// baseline (334.279 us; speedup 1.0000x reference)
//
#include <hip/hip_runtime.h>
#include <stdint.h>

// Problem constants (fixed by reference)
#define NXc 352
#define NYc 400
#define NZc 20
#define KS  11264000          // 4*20*400*352
#define NCH 64
#define SCAN_CHUNK 2048       // 256 threads * 8 elems
#define NBLK_SCAN 5500        // KS / SCAN_CHUNK (exact)

// ws layout (bytes), total ~57.1 MB
#define OFF_A     0ull
#define OFF_BP    45056000ull
#define OFF_BC    (OFF_BP + 22016ull)
#define OFF_NU    (OFF_BC + 22016ull)
#define OFF_KEY   (OFF_NU + 256ull)
#define OFF_IOFF  (OFF_KEY + 4000000ull)
#define OFF_PID   (OFF_IOFF + 4000256ull)

static __device__ __forceinline__ int keyof(int4 c) {
  return ((c.x * NZc + c.y) * NYc + c.z) * NXc + c.w;  // [b,z,y,x]
}

__global__ void k_count(const int4* __restrict__ coors, unsigned int* __restrict__ A, int n) {
  int p = blockIdx.x * 256 + threadIdx.x;
  if (p >= n) return;
  atomicAdd(&A[keyof(coors[p])], 1u);
}

__global__ void k_scan1(const unsigned int* __restrict__ A,
                        unsigned int* __restrict__ bp, unsigned int* __restrict__ bc) {
  int b = blockIdx.x, t = threadIdx.x;
  const uint4* A4 = (const uint4*)(A + (size_t)b * SCAN_CHUNK);
  uint4 v0 = A4[2 * t], v1 = A4[2 * t + 1];
  unsigned int pres = (v0.x > 0) + (v0.y > 0) + (v0.z > 0) + (v0.w > 0)
                    + (v1.x > 0) + (v1.y > 0) + (v1.z > 0) + (v1.w > 0);
  unsigned int cnt = v0.x + v0.y + v0.z + v0.w + v1.x + v1.y + v1.z + v1.w;
  __shared__ unsigned int sp[256], sc[256];
  sp[t] = pres; sc[t] = cnt; __syncthreads();
  for (int o = 128; o > 0; o >>= 1) {
    if (t < o) { sp[t] += sp[t + o]; sc[t] += sc[t + o]; }
    __syncthreads();
  }
  if (t == 0) { bp[b] = sp[0]; bc[b] = sc[0]; }
}

__global__ void k_scan2(unsigned int* __restrict__ bp, unsigned int* __restrict__ bc,
                        unsigned int* __restrict__ nu, unsigned int* __restrict__ ioff, int n) {
  int t = threadIdx.x;
  __shared__ unsigned int sp[256], sc[256];
  unsigned int cp = 0, cc = 0;
  for (int base = 0; base < NBLK_SCAN; base += 256) {
    int i = base + t;
    unsigned int vp = (i < NBLK_SCAN) ? bp[i] : 0u;
    unsigned int vc = (i < NBLK_SCAN) ? bc[i] : 0u;
    sp[t] = vp; sc[t] = vc; __syncthreads();
    unsigned int ipv = vp, icv = vc;
    for (int o = 1; o < 256; o <<= 1) {
      unsigned int ap = (t >= o) ? sp[t - o] : 0u;
      unsigned int ac = (t >= o) ? sc[t - o] : 0u;
      __syncthreads();
      ipv += ap; icv += ac;
      sp[t] = ipv; sc[t] = icv; __syncthreads();
    }
    if (i < NBLK_SCAN) { bp[i] = cp + ipv - vp; bc[i] = cc + icv - vc; }
    unsigned int tp = sp[255], tc = sc[255];
    __syncthreads();
    cp += tp; cc += tc;
  }
  if (t == 0) { nu[0] = cp; ioff[cp] = (unsigned int)n; }
}

__global__ void k_scan3(unsigned int* __restrict__ A,
                        const unsigned int* __restrict__ bp, const unsigned int* __restrict__ bc,
                        unsigned int* __restrict__ keyA, unsigned int* __restrict__ ioff) {
  int b = blockIdx.x, t = threadIdx.x;
  size_t base = (size_t)b * SCAN_CHUNK + (size_t)t * 8;
  uint4* A4 = (uint4*)(A + base);
  uint4 v0 = A4[0], v1 = A4[1];
  unsigned int c[8] = { v0.x, v0.y, v0.z, v0.w, v1.x, v1.y, v1.z, v1.w };
  unsigned int pres = 0, cnt = 0;
#pragma unroll
  for (int j = 0; j < 8; j++) { pres += (c[j] > 0); cnt += c[j]; }
  __shared__ unsigned int sp[256], sc[256];
  sp[t] = pres; sc[t] = cnt; __syncthreads();
  unsigned int ip = pres, ic = cnt;
  for (int o = 1; o < 256; o <<= 1) {
    unsigned int ap = (t >= o) ? sp[t - o] : 0u;
    unsigned int ac = (t >= o) ? sc[t - o] : 0u;
    __syncthreads();
    ip += ap; ic += ac;
    sp[t] = ip; sc[t] = ic; __syncthreads();
  }
  unsigned int rp = bp[b] + ip - pres;  // global exclusive presence prefix (rank)
  unsigned int rc = bc[b] + ic - cnt;   // global exclusive count prefix (CSR offset)
  unsigned int outv[8];
#pragma unroll
  for (int j = 0; j < 8; j++) {
    outv[j] = rc;
    if (c[j] > 0) {
      keyA[rp] = (unsigned int)(base + j);
      ioff[rp] = rc;
      rp++; rc += c[j];
    }
  }
  A4[0] = make_uint4(outv[0], outv[1], outv[2], outv[3]);
  A4[1] = make_uint4(outv[4], outv[5], outv[6], outv[7]);
}

__global__ void k_scatter(const int4* __restrict__ coors, unsigned int* __restrict__ A,
                          unsigned int* __restrict__ pid, int n) {
  int p = blockIdx.x * 256 + threadIdx.x;
  if (p >= n) return;
  unsigned int pos = atomicAdd(&A[keyof(coors[p])], 1u);
  pid[pos] = (unsigned int)p;
}

// 16 lanes per output row; row = 64 f32 channels (16 x float4 = 256 B)
__global__ void k_gather(const float4* __restrict__ pts, const unsigned int* __restrict__ pid,
                         const unsigned int* __restrict__ keyA, const unsigned int* __restrict__ ioff,
                         const unsigned int* __restrict__ nu, float* __restrict__ out, int n) {
  int gt = blockIdx.x * 256 + threadIdx.x;
  int r = gt >> 4, l = gt & 15;
  if (r >= n) return;
  unsigned int nU = nu[0];
  float4 acc = make_float4(0.f, 0.f, 0.f, 0.f);
  if ((unsigned int)r < nU) {
    unsigned int o0 = ioff[r], o1 = ioff[r + 1];
    float inv = 1.0f / (float)(o1 - o0);
    for (unsigned int i = o0; i < o1; i++) {
      unsigned int p = pid[i];
      float4 v = pts[(size_t)p * 16 + l];
      acc.x += v.x; acc.y += v.y; acc.z += v.z; acc.w += v.w;
    }
    acc.x *= inv; acc.y *= inv; acc.z *= inv; acc.w *= inv;
  }
  ((float4*)out)[(size_t)r * 16 + l] = acc;
  if (l == 0) {
    float* oc = out + (size_t)n * NCH + (size_t)r * 4;
    float4 cc4;
    if ((unsigned int)r < nU) {
      unsigned int k = keyA[r];
      unsigned int x = k % NXc; unsigned int k2 = k / NXc;
      unsigned int y = k2 % NYc; unsigned int k3 = k2 / NYc;
      unsigned int z = k3 % NZc; unsigned int bb = k3 / NZc;
      cc4 = make_float4((float)bb, (float)z, (float)y, (float)x);
    } else {
      cc4 = make_float4(-1.f, -1.f, -1.f, -1.f);
    }
    *((float4*)oc) = cc4;
  }
}

extern "C" void kernel_launch(void* const* d_in, const int* in_sizes, int n_in,
                              void* d_out, int out_size, void* d_ws, size_t ws_size,
                              hipStream_t stream) {
  const float4* pts = (const float4*)d_in[0];   // points: float32 (1M x 64)
  const int4* coors = (const int4*)d_in[1];
  int n = in_sizes[1] / 4;  // 1,000,000
  float* out = (float*)d_out;                   // float32 output (68M elements)
  char* ws = (char*)d_ws;
  unsigned int* A    = (unsigned int*)(ws + OFF_A);
  unsigned int* bp   = (unsigned int*)(ws + OFF_BP);
  unsigned int* bc   = (unsigned int*)(ws + OFF_BC);
  unsigned int* nu   = (unsigned int*)(ws + OFF_NU);
  unsigned int* keyA = (unsigned int*)(ws + OFF_KEY);
  unsigned int* ioff = (unsigned int*)(ws + OFF_IOFF);
  unsigned int* pid  = (unsigned int*)(ws + OFF_PID);

  hipMemsetAsync(A, 0, (size_t)KS * 4, stream);
  int nb = (n + 255) / 256;
  k_count  <<<nb,        256, 0, stream>>>(coors, A, n);
  k_scan1  <<<NBLK_SCAN, 256, 0, stream>>>(A, bp, bc);
  k_scan2  <<<1,         256, 0, stream>>>(bp, bc, nu, ioff, n);
  k_scan3  <<<NBLK_SCAN, 256, 0, stream>>>(A, bp, bc, keyA, ioff);
  k_scatter<<<nb,        256, 0, stream>>>(coors, A, pid, n);
  int gb = (n * 16 + 255) / 256;
  k_gather <<<gb,        256, 0, stream>>>(pts, pid, keyA, ioff, nu, out, n);
}

// Round 6
// 299.410 us; speedup vs baseline: 1.1165x; 1.1165x over previous
//
#include <hip/hip_runtime.h>
#include <stdint.h>

// Problem constants (fixed by reference)
#define NXc 352
#define NYc 400
#define NZc 20
#define KS  11264000          // 4*20*400*352
#define NCH 64
#define SCAN_CHUNK 2048       // 256 threads * 8 elems
#define NBLK_SCAN 5500        // KS / SCAN_CHUNK (exact)
#define RPT 4                 // rows per lane-group in k_gather

// ws layout (bytes), total ~57.1 MB
#define OFF_A     0ull
#define OFF_BP    45056000ull
#define OFF_BC    (OFF_BP + 22016ull)
#define OFF_NU    (OFF_BC + 22016ull)
#define OFF_KEY   (OFF_NU + 256ull)
#define OFF_IOFF  (OFF_KEY + 4000000ull)
#define OFF_PID   (OFF_IOFF + 4000256ull)

static __device__ __forceinline__ int keyof(int4 c) {
  return ((c.x * NZc + c.y) * NYc + c.z) * NXc + c.w;  // [b,z,y,x]
}

__global__ void k_count(const int4* __restrict__ coors, unsigned int* __restrict__ A, int n) {
  int p = blockIdx.x * 256 + threadIdx.x;
  if (p >= n) return;
  atomicAdd(&A[keyof(coors[p])], 1u);
}

__global__ void k_scan1(const unsigned int* __restrict__ A,
                        unsigned int* __restrict__ bp, unsigned int* __restrict__ bc) {
  int b = blockIdx.x, t = threadIdx.x;
  const uint4* A4 = (const uint4*)(A + (size_t)b * SCAN_CHUNK);
  uint4 v0 = A4[2 * t], v1 = A4[2 * t + 1];
  unsigned int pres = (v0.x > 0) + (v0.y > 0) + (v0.z > 0) + (v0.w > 0)
                    + (v1.x > 0) + (v1.y > 0) + (v1.z > 0) + (v1.w > 0);
  unsigned int cnt = v0.x + v0.y + v0.z + v0.w + v1.x + v1.y + v1.z + v1.w;
  __shared__ unsigned int sp[256], sc[256];
  sp[t] = pres; sc[t] = cnt; __syncthreads();
  for (int o = 128; o > 0; o >>= 1) {
    if (t < o) { sp[t] += sp[t + o]; sc[t] += sc[t + o]; }
    __syncthreads();
  }
  if (t == 0) { bp[b] = sp[0]; bc[b] = sc[0]; }
}

__global__ void k_scan2(unsigned int* __restrict__ bp, unsigned int* __restrict__ bc,
                        unsigned int* __restrict__ nu, unsigned int* __restrict__ ioff, int n) {
  int t = threadIdx.x;
  __shared__ unsigned int sp[256], sc[256];
  unsigned int cp = 0, cc = 0;
  for (int base = 0; base < NBLK_SCAN; base += 256) {
    int i = base + t;
    unsigned int vp = (i < NBLK_SCAN) ? bp[i] : 0u;
    unsigned int vc = (i < NBLK_SCAN) ? bc[i] : 0u;
    sp[t] = vp; sc[t] = vc; __syncthreads();
    unsigned int ipv = vp, icv = vc;
    for (int o = 1; o < 256; o <<= 1) {
      unsigned int ap = (t >= o) ? sp[t - o] : 0u;
      unsigned int ac = (t >= o) ? sc[t - o] : 0u;
      __syncthreads();
      ipv += ap; icv += ac;
      sp[t] = ipv; sc[t] = icv; __syncthreads();
    }
    if (i < NBLK_SCAN) { bp[i] = cp + ipv - vp; bc[i] = cc + icv - vc; }
    unsigned int tp = sp[255], tc = sc[255];
    __syncthreads();
    cp += tp; cc += tc;
  }
  if (t == 0) { nu[0] = cp; ioff[cp] = (unsigned int)n; }
}

__global__ void k_scan3(unsigned int* __restrict__ A,
                        const unsigned int* __restrict__ bp, const unsigned int* __restrict__ bc,
                        unsigned int* __restrict__ keyA, unsigned int* __restrict__ ioff) {
  int b = blockIdx.x, t = threadIdx.x;
  size_t base = (size_t)b * SCAN_CHUNK + (size_t)t * 8;
  uint4* A4 = (uint4*)(A + base);
  uint4 v0 = A4[0], v1 = A4[1];
  unsigned int c[8] = { v0.x, v0.y, v0.z, v0.w, v1.x, v1.y, v1.z, v1.w };
  unsigned int pres = 0, cnt = 0;
#pragma unroll
  for (int j = 0; j < 8; j++) { pres += (c[j] > 0); cnt += c[j]; }
  __shared__ unsigned int sp[256], sc[256];
  sp[t] = pres; sc[t] = cnt; __syncthreads();
  unsigned int ip = pres, ic = cnt;
  for (int o = 1; o < 256; o <<= 1) {
    unsigned int ap = (t >= o) ? sp[t - o] : 0u;
    unsigned int ac = (t >= o) ? sc[t - o] : 0u;
    __syncthreads();
    ip += ap; ic += ac;
    sp[t] = ip; sc[t] = ic; __syncthreads();
  }
  unsigned int rp = bp[b] + ip - pres;  // global exclusive presence prefix (rank)
  unsigned int rc = bc[b] + ic - cnt;   // global exclusive count prefix (CSR offset)
  unsigned int outv[8];
#pragma unroll
  for (int j = 0; j < 8; j++) {
    outv[j] = rc;
    if (c[j] > 0) {
      keyA[rp] = (unsigned int)(base + j);
      ioff[rp] = rc;
      rp++; rc += c[j];
    }
  }
  A4[0] = make_uint4(outv[0], outv[1], outv[2], outv[3]);
  A4[1] = make_uint4(outv[4], outv[5], outv[6], outv[7]);
}

__global__ void k_scatter(const int4* __restrict__ coors, unsigned int* __restrict__ A,
                          unsigned int* __restrict__ pid, int n) {
  int p = blockIdx.x * 256 + threadIdx.x;
  if (p >= n) return;
  unsigned int pos = atomicAdd(&A[keyof(coors[p])], 1u);
  pid[pos] = (unsigned int)p;
}

// 16 lanes per row; each lane-group owns RPT consecutive rows, phase-split
// loads so RPT independent HBM misses are in flight (G7: ILP to hide latency).
__global__ void k_gather(const float4* __restrict__ pts, const unsigned int* __restrict__ pid,
                         const unsigned int* __restrict__ keyA, const unsigned int* __restrict__ ioff,
                         const unsigned int* __restrict__ nu, float* __restrict__ out, int n) {
  int gt = blockIdx.x * 256 + threadIdx.x;
  int grp = gt >> 4, l = gt & 15;
  int rb = grp * RPT;
  if (rb >= n) return;
  unsigned int nU = nu[0];

  // phase 1: CSR bounds for RPT rows (clamped: rows >= nU get empty span)
  unsigned int e[RPT + 1];
#pragma unroll
  for (int j = 0; j <= RPT; j++) {
    unsigned int idx = min((unsigned int)(rb + j), nU);
    e[j] = ioff[idx];
  }

  // phase 2: first point id per row (predicated, independent)
  unsigned int p0[RPT];
#pragma unroll
  for (int j = 0; j < RPT; j++)
    p0[j] = (e[j] < e[j + 1]) ? pid[e[j]] : 0u;

  // phase 3: first point row (RPT independent 256-B random reads in flight)
  float4 acc[RPT];
#pragma unroll
  for (int j = 0; j < RPT; j++) {
    if (e[j] < e[j + 1]) acc[j] = pts[(size_t)p0[j] * 16 + l];
    else                 acc[j] = make_float4(0.f, 0.f, 0.f, 0.f);
  }

  // phase 4: rare tails (span > 1, ~4% of rows), then normalize
#pragma unroll
  for (int j = 0; j < RPT; j++) {
    unsigned int span = e[j + 1] - e[j];
    for (unsigned int i = e[j] + 1; i < e[j + 1]; i++) {
      unsigned int p = pid[i];
      float4 v = pts[(size_t)p * 16 + l];
      acc[j].x += v.x; acc[j].y += v.y; acc[j].z += v.z; acc[j].w += v.w;
    }
    if (span > 1) {
      float inv = 1.0f / (float)span;
      acc[j].x *= inv; acc[j].y *= inv; acc[j].z *= inv; acc[j].w *= inv;
    }
  }

  // write means (contiguous 256 B per row) + coors (lane 0: 64 B for RPT rows)
#pragma unroll
  for (int j = 0; j < RPT; j++) {
    int r = rb + j;
    if (r < n) ((float4*)out)[(size_t)r * 16 + l] = acc[j];
  }
  if (l == 0) {
#pragma unroll
    for (int j = 0; j < RPT; j++) {
      int r = rb + j;
      if (r >= n) break;
      float* oc = out + (size_t)n * NCH + (size_t)r * 4;
      float4 cc4;
      if ((unsigned int)r < nU) {
        unsigned int k = keyA[r];
        unsigned int x = k % NXc; unsigned int k2 = k / NXc;
        unsigned int y = k2 % NYc; unsigned int k3 = k2 / NYc;
        unsigned int z = k3 % NZc; unsigned int bb = k3 / NZc;
        cc4 = make_float4((float)bb, (float)z, (float)y, (float)x);
      } else {
        cc4 = make_float4(-1.f, -1.f, -1.f, -1.f);
      }
      *((float4*)oc) = cc4;
    }
  }
}

extern "C" void kernel_launch(void* const* d_in, const int* in_sizes, int n_in,
                              void* d_out, int out_size, void* d_ws, size_t ws_size,
                              hipStream_t stream) {
  const float4* pts = (const float4*)d_in[0];   // points: float32 (1M x 64)
  const int4* coors = (const int4*)d_in[1];
  int n = in_sizes[1] / 4;  // 1,000,000
  float* out = (float*)d_out;                   // float32 output (68M elements)
  char* ws = (char*)d_ws;
  unsigned int* A    = (unsigned int*)(ws + OFF_A);
  unsigned int* bp   = (unsigned int*)(ws + OFF_BP);
  unsigned int* bc   = (unsigned int*)(ws + OFF_BC);
  unsigned int* nu   = (unsigned int*)(ws + OFF_NU);
  unsigned int* keyA = (unsigned int*)(ws + OFF_KEY);
  unsigned int* ioff = (unsigned int*)(ws + OFF_IOFF);
  unsigned int* pid  = (unsigned int*)(ws + OFF_PID);

  hipMemsetAsync(A, 0, (size_t)KS * 4, stream);
  int nb = (n + 255) / 256;
  k_count  <<<nb,        256, 0, stream>>>(coors, A, n);
  k_scan1  <<<NBLK_SCAN, 256, 0, stream>>>(A, bp, bc);
  k_scan2  <<<1,         256, 0, stream>>>(bp, bc, nu, ioff, n);
  k_scan3  <<<NBLK_SCAN, 256, 0, stream>>>(A, bp, bc, keyA, ioff);
  k_scatter<<<nb,        256, 0, stream>>>(coors, A, pid, n);
  int ngrp = (n + RPT - 1) / RPT;               // lane-groups
  int gb = (ngrp * 16 + 255) / 256;
  k_gather <<<gb,        256, 0, stream>>>(pts, pid, keyA, ioff, nu, out, n);
}